// Round 1
// baseline (314.992 us; speedup 1.0000x reference)
//
#include <hip/hip_runtime.h>
#include <cstdint>
#include <cstddef>

#define N_CLS 80
#define TOPK 1000
#define SORT_N 2048
#define BD2 256

// ---------------- Kernel 1: decode boxes + per-anchor class score ----------
__global__ __launch_bounds__(256) void decode_kernel(
    const float* __restrict__ reg, const float* __restrict__ obj,
    const float* __restrict__ cls, const float* __restrict__ grid,
    const float* __restrict__ anch, const float* __restrict__ strd,
    float* __restrict__ boxes, float* __restrict__ scores,
    int* __restrict__ clsind, int N) {
  int i = blockIdx.x * blockDim.x + threadIdx.x;
  if (i >= N) return;
  const float4 r = ((const float4*)reg)[i];
  const float2 g = ((const float2*)grid)[i];
  const float2 a = ((const float2*)anch)[i];
  const float st = strd[i];

  float cx = (1.0f / (1.0f + expf(-r.x)) + g.x) * st;
  float cy = (1.0f / (1.0f + expf(-r.y)) + g.y) * st;
  float w = expf(r.z) * a.x;
  float h = expf(r.w) * a.y;
  float b0 = fminf(fmaxf((cx - 0.5f * w) / 640.0f, 0.0f), 1.0f);
  float b1 = fminf(fmaxf((cy - 0.5f * h) / 640.0f, 0.0f), 1.0f);
  float b2 = fminf(fmaxf((cx + 0.5f * w) / 640.0f, 0.0f), 1.0f);
  float b3 = fminf(fmaxf((cy + 0.5f * h) / 640.0f, 0.0f), 1.0f);
  float4 bo; bo.x = b0; bo.y = b1; bo.z = b2; bo.w = b3;
  ((float4*)boxes)[i] = bo;

  // softmax over 80 classes, then argmax/max of sigmoid(obj)*softmax with
  // first-occurrence tie semantics (matches jnp.argmax / jnp.max exactly).
  float x[N_CLS];
  const float4* cp = (const float4*)(cls + (size_t)i * N_CLS);
#pragma unroll
  for (int q = 0; q < N_CLS / 4; ++q) {
    float4 v = cp[q];
    x[4 * q + 0] = v.x; x[4 * q + 1] = v.y;
    x[4 * q + 2] = v.z; x[4 * q + 3] = v.w;
  }
  float mx = x[0];
#pragma unroll
  for (int c = 1; c < N_CLS; ++c) mx = fmaxf(mx, x[c]);
  float s = 0.0f;
#pragma unroll
  for (int c = 0; c < N_CLS; ++c) { float e = expf(x[c] - mx); x[c] = e; s += e; }
  float sig = 1.0f / (1.0f + expf(-obj[i]));
  float best = -1.0f; int bc = 0;
#pragma unroll
  for (int c = 0; c < N_CLS; ++c) {
    float q = sig * (x[c] / s);
    if (q > best) { best = q; bc = c; }
  }
  scores[i] = best;
  clsind[i] = bc;
}

// -------- Kernel 2: per-class top-k (JAX tie semantics) + greedy NMS -------
__global__ __launch_bounds__(BD2) void nms_kernel(
    const float* __restrict__ boxes, const float* __restrict__ scores,
    const int* __restrict__ clsind, float* __restrict__ out, int N) {
  const int c = blockIdx.x;
  const int tid = threadIdx.x;

  __shared__ float sv[SORT_N];
  __shared__ int si[SORT_N];
  __shared__ float bx0[TOPK], by0[TOPK], bx1[TOPK], by1[TOPK], bar[TOPK];
  __shared__ int kp[TOPK];
  __shared__ int cnt;
  __shared__ int wsum[BD2 / 64 + 1];

  if (tid == 0) cnt = 0;
  __syncthreads();

  // 1. collect positives for this class
  for (int i = tid; i < N; i += BD2) {
    if (clsind[i] == c && scores[i] >= 0.001f) {
      int p = atomicAdd(&cnt, 1);
      if (p < SORT_N) { sv[p] = scores[i]; si[p] = i; }
    }
  }
  __syncthreads();
  int count = min(cnt, SORT_N);
  for (int p = tid; p < SORT_N; p += BD2)
    if (p >= count) { sv[p] = -1e30f; si[p] = 0x7fffffff; }

  // 2. bitonic sort: value desc, ties -> index asc (== jax.lax.top_k order)
  for (int k = 2; k <= SORT_N; k <<= 1) {
    for (int j = k >> 1; j > 0; j >>= 1) {
      __syncthreads();
      for (int t = tid; t < SORT_N; t += BD2) {
        int ixj = t ^ j;
        if (ixj > t) {
          float v1 = sv[t], v2 = sv[ixj];
          int i1 = si[t], i2 = si[ixj];
          bool bef = (v1 > v2) || (v1 == v2 && i1 < i2);
          bool up = ((t & k) == 0);
          if (up ? !bef : bef) {
            sv[t] = v2; sv[ixj] = v1; si[t] = i2; si[ixj] = i1;
          }
        }
      }
    }
  }
  __syncthreads();
  int m = min(count, TOPK);

  // 3. fillers: lowest-index anchors with s_c == -1.0, ascending (top_k tie
  //    order among the -1.0 entries). Ballot-based block prefix scan.
  int M = TOPK - m;
  if (M > 0) {
    int carry = 0;
    for (int base = 0; base < N && carry < M; base += BD2) {
      int i = base + tid;
      bool f = (i < N) && !(clsind[i] == c && scores[i] >= 0.001f);
      unsigned long long mk = __ballot(f ? 1 : 0);
      int lane = tid & 63;
      int wv = tid >> 6;
      int pre = __popcll(mk & ((1ULL << lane) - 1ULL));
      if (lane == 0) wsum[wv] = __popcll(mk);
      __syncthreads();
      if (tid == 0) {
        int acc = 0;
        for (int wq = 0; wq < BD2 / 64; ++wq) { int t = wsum[wq]; wsum[wq] = acc; acc += t; }
        wsum[BD2 / 64] = acc;
      }
      __syncthreads();
      int pos = carry + wsum[wv] + pre;
      if (f && pos < M) si[m + pos] = i;
      carry += wsum[BD2 / 64];
      __syncthreads();
    }
  }
  __syncthreads();

  // 4. gather boxes, init keep (valid = vals > 0 <=> t < m)
  for (int t = tid; t < TOPK; t += BD2) {
    int idx = si[t];
    float a0 = boxes[4 * idx + 0], a1 = boxes[4 * idx + 1];
    float a2 = boxes[4 * idx + 2], a3 = boxes[4 * idx + 3];
    bx0[t] = a0; by0[t] = a1; bx1[t] = a2; by1[t] = a3;
    bar[t] = (a2 - a0) * (a3 - a1);
    kp[t] = (t < m) ? 1 : 0;
  }
  __syncthreads();

  // 5. greedy NMS (exact reference semantics: only still-kept i suppress)
  for (int i = 0; i < m; ++i) {
    if (kp[i]) {
      float xi0 = bx0[i], yi0 = by0[i], xi1 = bx1[i], yi1 = by1[i], ai = bar[i];
      for (int j = i + 1 + tid; j < m; j += BD2) {
        if (kp[j]) {
          float xx1 = fmaxf(xi0, bx0[j]);
          float yy1 = fmaxf(yi0, by0[j]);
          float xx2 = fminf(xi1, bx1[j]);
          float yy2 = fminf(yi1, by1[j]);
          float w = fmaxf(1e-28f, xx2 - xx1);
          float h = fmaxf(1e-28f, yy2 - yy1);
          float inter = w * h;
          float iou = inter / (ai + bar[j] - inter + 1e-14f);
          if (iou > 0.6f) kp[j] = 0;
        }
      }
    }
    __syncthreads();
  }

  // 6. write outputs: boxes [80,1000,4], scores*keep [80,1000], keep [80,1000]
  float* outB = out;
  float* outS = out + N_CLS * TOPK * 4;
  float* outK = outS + N_CLS * TOPK;
  for (int t = tid; t < TOPK; t += BD2) {
    float v = (t < m) ? sv[t] : -1.0f;
    float k = (float)kp[t];
    outB[(c * TOPK + t) * 4 + 0] = bx0[t];
    outB[(c * TOPK + t) * 4 + 1] = by0[t];
    outB[(c * TOPK + t) * 4 + 2] = bx1[t];
    outB[(c * TOPK + t) * 4 + 3] = by1[t];
    outS[c * TOPK + t] = v * k;
    outK[c * TOPK + t] = k;
  }
}

extern "C" void kernel_launch(void* const* d_in, const int* in_sizes, int n_in,
                              void* d_out, int out_size, void* d_ws, size_t ws_size,
                              hipStream_t stream) {
  const float* reg  = (const float*)d_in[0];
  const float* obj  = (const float*)d_in[1];
  const float* cls  = (const float*)d_in[2];
  const float* grid = (const float*)d_in[3];
  const float* anch = (const float*)d_in[4];
  const float* strd = (const float*)d_in[5];
  const int N = in_sizes[0] / 4;  // 25200

  float* boxes  = (float*)d_ws;                 // N*4 floats
  float* scores = boxes + (size_t)N * 4;        // N floats
  int*   clsind = (int*)(scores + N);           // N ints
  float* out    = (float*)d_out;

  decode_kernel<<<(N + 255) / 256, 256, 0, stream>>>(
      reg, obj, cls, grid, anch, strd, boxes, scores, clsind, N);
  nms_kernel<<<N_CLS, BD2, 0, stream>>>(boxes, scores, clsind, out, N);
}

// Round 2
// 291.729 us; speedup vs baseline: 1.0797x; 1.0797x over previous
//
#include <hip/hip_runtime.h>
#include <cstdint>
#include <cstddef>

#define N_CLS 80
#define TOPK 1000
#define POOL_N 2048   // max collected positives per class
#define MCAP 512      // bitmask-NMS capacity (m <= MCAP); else fallback loop
#define WRDS 8        // MCAP/64 words per bitmask row
#define BD2 256

// ---------------- Kernel 1: decode boxes + per-anchor class score ----------
// (unchanged from round 1 — bit-exact vs reference, absmax 0.0)
__global__ __launch_bounds__(256) void decode_kernel(
    const float* __restrict__ reg, const float* __restrict__ obj,
    const float* __restrict__ cls, const float* __restrict__ grid,
    const float* __restrict__ anch, const float* __restrict__ strd,
    float* __restrict__ boxes, float* __restrict__ scores,
    int* __restrict__ clsind, int N) {
  int i = blockIdx.x * blockDim.x + threadIdx.x;
  if (i >= N) return;
  const float4 r = ((const float4*)reg)[i];
  const float2 g = ((const float2*)grid)[i];
  const float2 a = ((const float2*)anch)[i];
  const float st = strd[i];

  float cx = (1.0f / (1.0f + expf(-r.x)) + g.x) * st;
  float cy = (1.0f / (1.0f + expf(-r.y)) + g.y) * st;
  float w = expf(r.z) * a.x;
  float h = expf(r.w) * a.y;
  float b0 = fminf(fmaxf((cx - 0.5f * w) / 640.0f, 0.0f), 1.0f);
  float b1 = fminf(fmaxf((cy - 0.5f * h) / 640.0f, 0.0f), 1.0f);
  float b2 = fminf(fmaxf((cx + 0.5f * w) / 640.0f, 0.0f), 1.0f);
  float b3 = fminf(fmaxf((cy + 0.5f * h) / 640.0f, 0.0f), 1.0f);
  float4 bo; bo.x = b0; bo.y = b1; bo.z = b2; bo.w = b3;
  ((float4*)boxes)[i] = bo;

  float x[N_CLS];
  const float4* cp = (const float4*)(cls + (size_t)i * N_CLS);
#pragma unroll
  for (int q = 0; q < N_CLS / 4; ++q) {
    float4 v = cp[q];
    x[4 * q + 0] = v.x; x[4 * q + 1] = v.y;
    x[4 * q + 2] = v.z; x[4 * q + 3] = v.w;
  }
  float mx = x[0];
#pragma unroll
  for (int c = 1; c < N_CLS; ++c) mx = fmaxf(mx, x[c]);
  float s = 0.0f;
#pragma unroll
  for (int c = 0; c < N_CLS; ++c) { float e = expf(x[c] - mx); x[c] = e; s += e; }
  float sig = 1.0f / (1.0f + expf(-obj[i]));
  float best = -1.0f; int bc = 0;
#pragma unroll
  for (int c = 0; c < N_CLS; ++c) {
    float q = sig * (x[c] / s);
    if (q > best) { best = q; bc = c; }
  }
  scores[i] = best;
  clsind[i] = bc;
}

// -------- Kernel 2: per-class top-k (rank sort) + bitmask greedy NMS -------
__global__ __launch_bounds__(BD2) void nms_kernel(
    const float* __restrict__ boxes, const float* __restrict__ scores,
    const int* __restrict__ clsind, float* __restrict__ out, int N) {
  const int c = blockIdx.x;
  const int tid = threadIdx.x;

  // union: sort pool (16KB) lives before bitmat (32KB) is needed
  __shared__ __align__(16) unsigned char upool[MCAP * WRDS * 8];  // 32768 B
  float* sv = (float*)upool;                          // [POOL_N]
  int* si = (int*)(upool + POOL_N * 4);               // [POOL_N]
  unsigned long long* bitmat = (unsigned long long*)upool;  // [MCAP*WRDS]

  __shared__ float svals[TOPK];
  __shared__ int sidx[TOPK];
  __shared__ float bx0[TOPK], by0[TOPK], bx1[TOPK], by1[TOPK], bar[TOPK];
  __shared__ unsigned char kp[TOPK];                  // fallback path only
  __shared__ unsigned long long kpw[WRDS];
  __shared__ int cnt;
  __shared__ int wsum[BD2 / 64 + 1];

  if (tid == 0) cnt = 0;
  __syncthreads();

  // 1. collect positives for this class
  for (int i = tid; i < N; i += BD2) {
    if (clsind[i] == c && scores[i] >= 0.001f) {
      int p = atomicAdd(&cnt, 1);
      if (p < POOL_N) { sv[p] = scores[i]; si[p] = i; }
    }
  }
  __syncthreads();
  const int count = min(cnt, POOL_N);
  const int m = min(count, TOPK);

  // 2. rank sort: rank = #elements before (value desc, ties -> index asc)
  //    == jax.lax.top_k order. O(count^2) but barrier-free; count ~312.
  for (int e = tid; e < count; e += BD2) {
    float v = sv[e];
    int idx = si[e];
    int r = 0;
    for (int k = 0; k < count; ++k) {
      float vk = sv[k];
      int ik = si[k];
      r += (int)((vk > v) || (vk == v && ik < idx));
    }
    if (r < TOPK) { svals[r] = v; sidx[r] = idx; }
  }
  __syncthreads();

  // 3. fillers: lowest-index anchors with s_c == -1.0, ascending order
  const int M = TOPK - m;
  if (M > 0) {
    int carry = 0;
    for (int base = 0; base < N && carry < M; base += BD2) {
      int i = base + tid;
      bool f = (i < N) && !(clsind[i] == c && scores[i] >= 0.001f);
      unsigned long long mk = __ballot(f ? 1 : 0);
      int lane = tid & 63;
      int wv = tid >> 6;
      int pre = __popcll(mk & ((1ULL << lane) - 1ULL));
      if (lane == 0) wsum[wv] = __popcll(mk);
      __syncthreads();
      if (tid == 0) {
        int acc = 0;
        for (int wq = 0; wq < BD2 / 64; ++wq) { int t = wsum[wq]; wsum[wq] = acc; acc += t; }
        wsum[BD2 / 64] = acc;
      }
      __syncthreads();
      int pos = carry + wsum[wv] + pre;
      if (f && pos < M) sidx[m + pos] = i;
      carry += wsum[BD2 / 64];
      __syncthreads();
    }
  }
  __syncthreads();

  // 4. gather boxes (sort pool sv/si is dead from here -> bitmat may reuse)
  for (int t = tid; t < TOPK; t += BD2) {
    int idx = sidx[t];
    float a0 = boxes[4 * idx + 0], a1 = boxes[4 * idx + 1];
    float a2 = boxes[4 * idx + 2], a3 = boxes[4 * idx + 3];
    bx0[t] = a0; by0[t] = a1; bx1[t] = a2; by1[t] = a3;
    bar[t] = (a2 - a0) * (a3 - a1);
  }
  __syncthreads();

  if (m <= MCAP) {
    // 5a. build bitmask matrix: row i, bit j set iff j>i and iou(i,j)>0.6
    const int W = (m + 63) >> 6;
    for (int q = tid; q < m * W; q += BD2) {
      int w = q / m;        // adjacent threads -> same word, adjacent rows
      int row = q % m;      // -> bx*[j] reads broadcast across the wave
      float xi0 = bx0[row], yi0 = by0[row], xi1 = bx1[row], yi1 = by1[row];
      float ai = bar[row];
      unsigned long long bits = 0ULL;
      int j0 = w << 6;
      int jend = min(j0 + 64, m);
      for (int j = j0; j < jend; ++j) {
        if (j > row) {
          float xx1 = fmaxf(xi0, bx0[j]);
          float yy1 = fmaxf(yi0, by0[j]);
          float xx2 = fminf(xi1, bx1[j]);
          float yy2 = fminf(yi1, by1[j]);
          float ww = fmaxf(1e-28f, xx2 - xx1);
          float hh = fmaxf(1e-28f, yy2 - yy1);
          float inter = ww * hh;
          float iou = inter / (ai + bar[j] - inter + 1e-14f);
          if (iou > 0.6f) bits |= (1ULL << (j - j0));
        }
      }
      bitmat[row * WRDS + w] = bits;
    }
    __syncthreads();

    // 6a. exact greedy scan, one wave, registers only (no barriers inside).
    if (tid < 64) {
      unsigned long long km[WRDS];
#pragma unroll
      for (int u = 0; u < WRDS; ++u) {
        int lo = u << 6;
        km[u] = (m <= lo) ? 0ULL
                          : ((m - lo >= 64) ? ~0ULL : ((1ULL << (m - lo)) - 1ULL));
      }
#pragma unroll
      for (int w = 0; w < WRDS; ++w) {
        if ((w << 6) < m) {
          for (int b = 0; b < 64; ++b) {
            int i = (w << 6) + b;
            if (i >= m) break;
            if ((km[w] >> b) & 1ULL) {
              const ulonglong2* rp = (const ulonglong2*)&bitmat[i * WRDS];
              ulonglong2 r0 = rp[0], r1 = rp[1], r2 = rp[2], r3 = rp[3];
              km[0] &= ~r0.x; km[1] &= ~r0.y;
              km[2] &= ~r1.x; km[3] &= ~r1.y;
              km[4] &= ~r2.x; km[5] &= ~r2.y;
              km[6] &= ~r3.x; km[7] &= ~r3.y;
            }
          }
        }
      }
      if (tid == 0) {
        kpw[0] = km[0]; kpw[1] = km[1]; kpw[2] = km[2]; kpw[3] = km[3];
        kpw[4] = km[4]; kpw[5] = km[5]; kpw[6] = km[6]; kpw[7] = km[7];
      }
    }
    __syncthreads();
  } else {
    // 5b/6b. fallback (m > MCAP; never hit on this data): serial barrier loop
    for (int t = tid; t < TOPK; t += BD2) kp[t] = (t < m) ? 1 : 0;
    __syncthreads();
    for (int i = 0; i < m; ++i) {
      if (kp[i]) {
        float xi0 = bx0[i], yi0 = by0[i], xi1 = bx1[i], yi1 = by1[i], ai = bar[i];
        for (int j = i + 1 + tid; j < m; j += BD2) {
          if (kp[j]) {
            float xx1 = fmaxf(xi0, bx0[j]);
            float yy1 = fmaxf(yi0, by0[j]);
            float xx2 = fminf(xi1, bx1[j]);
            float yy2 = fminf(yi1, by1[j]);
            float ww = fmaxf(1e-28f, xx2 - xx1);
            float hh = fmaxf(1e-28f, yy2 - yy1);
            float inter = ww * hh;
            float iou = inter / (ai + bar[j] - inter + 1e-14f);
            if (iou > 0.6f) kp[j] = 0;
          }
        }
      }
      __syncthreads();
    }
  }

  // 7. outputs: boxes [80,1000,4], scores*keep [80,1000], keep [80,1000]
  float* outB = out;
  float* outS = out + N_CLS * TOPK * 4;
  float* outK = outS + N_CLS * TOPK;
  const bool pathA = (m <= MCAP);
  for (int t = tid; t < TOPK; t += BD2) {
    float k;
    if (t < m)
      k = pathA ? (float)((kpw[t >> 6] >> (t & 63)) & 1ULL) : (float)kp[t];
    else
      k = 0.0f;
    float v = (t < m) ? svals[t] : -1.0f;
    float4 bo; bo.x = bx0[t]; bo.y = by0[t]; bo.z = bx1[t]; bo.w = by1[t];
    ((float4*)outB)[c * TOPK + t] = bo;
    outS[c * TOPK + t] = v * k;
    outK[c * TOPK + t] = k;
  }
}

extern "C" void kernel_launch(void* const* d_in, const int* in_sizes, int n_in,
                              void* d_out, int out_size, void* d_ws, size_t ws_size,
                              hipStream_t stream) {
  const float* reg  = (const float*)d_in[0];
  const float* obj  = (const float*)d_in[1];
  const float* cls  = (const float*)d_in[2];
  const float* grid = (const float*)d_in[3];
  const float* anch = (const float*)d_in[4];
  const float* strd = (const float*)d_in[5];
  const int N = in_sizes[0] / 4;  // 25200

  float* boxes  = (float*)d_ws;                 // N*4 floats
  float* scores = boxes + (size_t)N * 4;        // N floats
  int*   clsind = (int*)(scores + N);           // N ints
  float* out    = (float*)d_out;

  decode_kernel<<<(N + 255) / 256, 256, 0, stream>>>(
      reg, obj, cls, grid, anch, strd, boxes, scores, clsind, N);
  nms_kernel<<<N_CLS, BD2, 0, stream>>>(boxes, scores, clsind, out, N);
}

// Round 3
// 170.193 us; speedup vs baseline: 1.8508x; 1.7141x over previous
//
#include <hip/hip_runtime.h>
#include <cstdint>
#include <cstddef>

#define N_CLS 80
#define TOPK 1000
#define POOL_N 2048
#define MCAP 512
#define WRDS 8
#define BD 1024
#define DTB 64

// ---------------- Kernel 1: decode + score, LDS-staged cls reads -----------
// Per-thread arithmetic identical to round-1/2 (bit-exact, absmax 0.0); only
// the load path for cls changed: coalesced global -> LDS tile (stride 84
// floats = 21 float4 to break the 80-float power-pattern bank conflicts).
__global__ __launch_bounds__(DTB) void decode_kernel(
    const float* __restrict__ reg, const float* __restrict__ obj,
    const float* __restrict__ cls, const float* __restrict__ grid,
    const float* __restrict__ anch, const float* __restrict__ strd,
    float* __restrict__ boxes, uint2* __restrict__ scs, int N) {
  __shared__ __align__(16) float tile[DTB * 84];
  const int tb = blockIdx.x * DTB;
  const int na = min(DTB, N - tb);
  const int nf4 = na * 20;
  const float4* cg = (const float4*)cls + (size_t)tb * 20;
  float4* tf4 = (float4*)tile;
  for (int j = threadIdx.x; j < nf4; j += DTB) {
    int a = j / 20;          // const divisor -> magic-mul
    int p = j - a * 20;
    tf4[a * 21 + p] = cg[j]; // cg[j]: lane-consecutive -> 1KB coalesced
  }
  __syncthreads();

  const int t = threadIdx.x;
  const int i = tb + t;
  if (i >= N) return;

  const float4 r = ((const float4*)reg)[i];
  const float2 g = ((const float2*)grid)[i];
  const float2 aw = ((const float2*)anch)[i];
  const float st = strd[i];

  float cx = (1.0f / (1.0f + expf(-r.x)) + g.x) * st;
  float cy = (1.0f / (1.0f + expf(-r.y)) + g.y) * st;
  float w = expf(r.z) * aw.x;
  float h = expf(r.w) * aw.y;
  float b0 = fminf(fmaxf((cx - 0.5f * w) / 640.0f, 0.0f), 1.0f);
  float b1 = fminf(fmaxf((cy - 0.5f * h) / 640.0f, 0.0f), 1.0f);
  float b2 = fminf(fmaxf((cx + 0.5f * w) / 640.0f, 0.0f), 1.0f);
  float b3 = fminf(fmaxf((cy + 0.5f * h) / 640.0f, 0.0f), 1.0f);
  float4 bo; bo.x = b0; bo.y = b1; bo.z = b2; bo.w = b3;
  ((float4*)boxes)[i] = bo;

  float x[N_CLS];
#pragma unroll
  for (int q = 0; q < N_CLS / 4; ++q) {
    float4 v = tf4[t * 21 + q];
    x[4 * q + 0] = v.x; x[4 * q + 1] = v.y;
    x[4 * q + 2] = v.z; x[4 * q + 3] = v.w;
  }
  float mx = x[0];
#pragma unroll
  for (int c = 1; c < N_CLS; ++c) mx = fmaxf(mx, x[c]);
  float s = 0.0f;
#pragma unroll
  for (int c = 0; c < N_CLS; ++c) { float e = expf(x[c] - mx); x[c] = e; s += e; }
  float sig = 1.0f / (1.0f + expf(-obj[i]));
  float best = -1.0f; int bc = 0;
#pragma unroll
  for (int c = 0; c < N_CLS; ++c) {
    float q = sig * (x[c] / s);
    if (q > best) { best = q; bc = c; }
  }
  scs[i] = make_uint2(__float_as_uint(best), (unsigned)bc);
}

// -------- Kernel 2: per-class top-k (rank sort) + bitmask greedy NMS -------
__global__ __launch_bounds__(BD) void nms_kernel(
    const float* __restrict__ boxes, const uint2* __restrict__ scs,
    float* __restrict__ out, int N) {
  const int c = blockIdx.x;
  const int tid = threadIdx.x;

  // union: collect pool (16KB max) | bitmask matrix (32KB) | fallback kp
  __shared__ __align__(16) unsigned char upool[MCAP * WRDS * 8];  // 32768 B
  uint2* pool = (uint2*)upool;                       // [POOL_N] (score,idx)
  unsigned long long* bitmat = (unsigned long long*)upool;  // [MCAP*WRDS]
  unsigned char* kp = (unsigned char*)upool;         // fallback only

  __shared__ float svals[TOPK];
  __shared__ int sidx[TOPK];
  __shared__ __align__(16) float4 bxyz[TOPK];        // 16 KB
  __shared__ unsigned long long kpw[WRDS];
  __shared__ int cnt;
  __shared__ int wsum[BD / 64 + 1];

  if (tid == 0) cnt = 0;
  __syncthreads();

  // 1. collect positives (one coalesced b64 per anchor)
  for (int i = tid; i < N; i += BD) {
    uint2 sc = scs[i];
    if (sc.y == (unsigned)c && __uint_as_float(sc.x) >= 0.001f) {
      int p = atomicAdd(&cnt, 1);
      if (p < POOL_N) pool[p] = make_uint2(sc.x, (unsigned)i);
    }
  }
  __syncthreads();
  const int count = min(cnt, POOL_N);
  const int m = min(count, TOPK);

  // 2. rank sort: value desc, ties -> index asc (== jax.lax.top_k order)
  for (int e = tid; e < count; e += BD) {
    uint2 me = pool[e];
    float v = __uint_as_float(me.x);
    int idx = (int)me.y;
    int r = 0;
#pragma unroll 4
    for (int k = 0; k < count; ++k) {
      uint2 q = pool[k];
      float vk = __uint_as_float(q.x);
      r += (int)((vk > v) || (vk == v && (int)q.y < idx));
    }
    if (r < TOPK) { svals[r] = v; sidx[r] = idx; }
  }
  __syncthreads();

  // 3. fillers: lowest-index non-matching anchors, ascending
  const int M = TOPK - m;
  if (M > 0) {
    int carry = 0;
    for (int base = 0; base < N && carry < M; base += BD) {
      int i = base + tid;
      bool f = false;
      if (i < N) {
        uint2 sc = scs[i];
        f = !(sc.y == (unsigned)c && __uint_as_float(sc.x) >= 0.001f);
      }
      unsigned long long mk = __ballot(f ? 1 : 0);
      int lane = tid & 63, wv = tid >> 6;
      int pre = __popcll(mk & ((1ULL << lane) - 1ULL));
      if (lane == 0) wsum[wv] = __popcll(mk);
      __syncthreads();
      if (tid == 0) {
        int acc = 0;
        for (int wq = 0; wq < BD / 64; ++wq) { int t2 = wsum[wq]; wsum[wq] = acc; acc += t2; }
        wsum[BD / 64] = acc;
      }
      __syncthreads();
      int pos = carry + wsum[wv] + pre;
      if (f && pos < M) sidx[m + pos] = i;
      carry += wsum[BD / 64];
      __syncthreads();
    }
  }
  __syncthreads();

  // 4. gather boxes as float4 (pool region dead after sort)
  const float4* bf4 = (const float4*)boxes;
  for (int t = tid; t < TOPK; t += BD) bxyz[t] = bf4[sidx[t]];
  __syncthreads();

  if (m <= MCAP) {
    // 5a. zero bitmat, then build upper-triangle iou>0.6 bitmask
    for (int u = tid; u < MCAP * WRDS; u += BD) bitmat[u] = 0ULL;
    __syncthreads();
    const int W = (m + 63) >> 6;
    for (int q = tid; q < m * W; q += BD) {
      int w = q / m;
      int row = q - w * m;
      if (w < (row >> 6)) continue;   // lower-triangle word: stays zero
      float4 rb = bxyz[row];
      float ai = (rb.z - rb.x) * (rb.w - rb.y);
      unsigned long long bits = 0ULL;
      int j0 = w << 6;
      int jend = min(j0 + 64, m);
      for (int j = max(j0, row + 1); j < jend; ++j) {
        float4 jb = bxyz[j];                       // one ds_read_b128
        float aj = (jb.z - jb.x) * (jb.w - jb.y);
        float xx1 = fmaxf(rb.x, jb.x), yy1 = fmaxf(rb.y, jb.y);
        float xx2 = fminf(rb.z, jb.z), yy2 = fminf(rb.w, jb.w);
        float ww = fmaxf(1e-28f, xx2 - xx1), hh = fmaxf(1e-28f, yy2 - yy1);
        float inter = ww * hh;
        float iou = inter / (ai + aj - inter + 1e-14f);
        if (iou > 0.6f) bits |= (1ULL << (j - j0));
      }
      bitmat[row * WRDS + w] = bits;
    }
    __syncthreads();

    // 6a. exact greedy scan, one wave, next-row prefetch hides LDS latency
    if (tid < 64) {
      unsigned long long km[WRDS];
#pragma unroll
      for (int u = 0; u < WRDS; ++u) {
        int lo = u << 6;
        km[u] = (m <= lo) ? 0ULL
                          : ((m - lo >= 64) ? ~0ULL : ((1ULL << (m - lo)) - 1ULL));
      }
      const ulonglong2* rp = (const ulonglong2*)bitmat;
      ulonglong2 c0, c1, c2, c3;
      if (m > 0) { c0 = rp[0]; c1 = rp[1]; c2 = rp[2]; c3 = rp[3]; }
#pragma unroll
      for (int w = 0; w < WRDS; ++w) {
        if ((w << 6) < m) {
          for (int b = 0; b < 64; ++b) {
            int i = (w << 6) + b;
            if (i >= m) break;
            int nr = min(i + 1, MCAP - 1);          // stay in-bounds
            const ulonglong2* np = rp + (size_t)nr * 4;
            ulonglong2 n0 = np[0], n1 = np[1], n2 = np[2], n3 = np[3];
            if ((km[w] >> b) & 1ULL) {
              km[0] &= ~c0.x; km[1] &= ~c0.y; km[2] &= ~c1.x; km[3] &= ~c1.y;
              km[4] &= ~c2.x; km[5] &= ~c2.y; km[6] &= ~c3.x; km[7] &= ~c3.y;
            }
            c0 = n0; c1 = n1; c2 = n2; c3 = n3;
          }
        }
      }
      if (tid == 0) {
#pragma unroll
        for (int u = 0; u < WRDS; ++u) kpw[u] = km[u];
      }
    }
    __syncthreads();
  } else {
    // 5b/6b. fallback (m > MCAP; not hit on this data): serial barrier loop
    for (int t = tid; t < TOPK; t += BD) kp[t] = (t < m) ? 1 : 0;
    __syncthreads();
    for (int i = 0; i < m; ++i) {
      if (kp[i]) {
        float4 rb = bxyz[i];
        float ai = (rb.z - rb.x) * (rb.w - rb.y);
        for (int j = i + 1 + tid; j < m; j += BD) {
          if (kp[j]) {
            float4 jb = bxyz[j];
            float aj = (jb.z - jb.x) * (jb.w - jb.y);
            float xx1 = fmaxf(rb.x, jb.x), yy1 = fmaxf(rb.y, jb.y);
            float xx2 = fminf(rb.z, jb.z), yy2 = fminf(rb.w, jb.w);
            float ww = fmaxf(1e-28f, xx2 - xx1), hh = fmaxf(1e-28f, yy2 - yy1);
            float inter = ww * hh;
            float iou = inter / (ai + aj - inter + 1e-14f);
            if (iou > 0.6f) kp[j] = 0;
          }
        }
      }
      __syncthreads();
    }
  }

  // 7. outputs: boxes [80,1000,4], scores*keep [80,1000], keep [80,1000]
  float* outB = out;
  float* outS = out + N_CLS * TOPK * 4;
  float* outK = outS + N_CLS * TOPK;
  const bool pathA = (m <= MCAP);
  for (int t = tid; t < TOPK; t += BD) {
    float k;
    if (t < m)
      k = pathA ? (float)((kpw[t >> 6] >> (t & 63)) & 1ULL) : (float)kp[t];
    else
      k = 0.0f;
    float v = (t < m) ? svals[t] : -1.0f;
    ((float4*)outB)[c * TOPK + t] = bxyz[t];
    outS[c * TOPK + t] = v * k;
    outK[c * TOPK + t] = k;
  }
}

extern "C" void kernel_launch(void* const* d_in, const int* in_sizes, int n_in,
                              void* d_out, int out_size, void* d_ws, size_t ws_size,
                              hipStream_t stream) {
  const float* reg  = (const float*)d_in[0];
  const float* obj  = (const float*)d_in[1];
  const float* cls  = (const float*)d_in[2];
  const float* grid = (const float*)d_in[3];
  const float* anch = (const float*)d_in[4];
  const float* strd = (const float*)d_in[5];
  const int N = in_sizes[0] / 4;  // 25200

  float* boxes = (float*)d_ws;                       // N*4 floats
  uint2* scs   = (uint2*)(boxes + (size_t)N * 4);    // N uint2 (score,cls)
  float* out   = (float*)d_out;

  decode_kernel<<<(N + DTB - 1) / DTB, DTB, 0, stream>>>(
      reg, obj, cls, grid, anch, strd, boxes, scs, N);
  nms_kernel<<<N_CLS, BD, 0, stream>>>(boxes, scs, out, N);
}